// Round 5
// baseline (76.116 us; speedup 1.0000x reference)
//
#include <hip/hip_runtime.h>
#include <cmath>

#define Bn 8
#define Tn 2048
#define Cn 1024
#define Kn 128

typedef __attribute__((ext_vector_type(8))) short short8;
typedef __attribute__((ext_vector_type(4))) float f32x4;
typedef unsigned short u16;
typedef unsigned int u32;

#define NEGINF (-__builtin_huge_valf())

__device__ __forceinline__ u16 f2b(float f) {
    u32 u = __float_as_uint(f);
    u32 r = (u + 0x7FFFu + ((u >> 16) & 1u)) >> 16;
    return (u16)r;
}
__device__ __forceinline__ float b2f(u16 v) {
    u32 u = ((u32)v) << 16;
    return __uint_as_float(u);
}

__device__ __forceinline__ void load_lds16(const u16* g, u16* l) {
    __builtin_amdgcn_global_load_lds(
        (const __attribute__((address_space(1))) u32*)(g),
        (__attribute__((address_space(3))) u32*)(l), 16, 0, 0);
}

// ---------------------------------------------------------------------------
// prep: W [1024 c][128 n] fp32 -> W^T bf16 [3][128 n][1024 c]   (fallback path)
// ---------------------------------------------------------------------------
__global__ __launch_bounds__(256)
void prep_kernel(const float* __restrict__ Wq, const float* __restrict__ Wk,
                 const float* __restrict__ Wv, u16* __restrict__ Wt)
{
    int id = blockIdx.x * 256 + threadIdx.x;
    int w   = id >> 15;
    int rem = id & 32767;
    int c   = rem >> 5;
    int n4  = (rem & 31) << 2;
    const float* W = (w == 0) ? Wq : (w == 1) ? Wk : Wv;
    float4 v = *(const float4*)(W + (size_t)c * Kn + n4);
    u16* dst = Wt + (size_t)w * Kn * Cn;
    dst[(size_t)(n4 + 0) * Cn + c] = f2b(v.x);
    dst[(size_t)(n4 + 1) * Cn + c] = f2b(v.y);
    dst[(size_t)(n4 + 2) * Cn + c] = f2b(v.z);
    dst[(size_t)(n4 + 3) * Cn + c] = f2b(v.w);
}

// ---------------------------------------------------------------------------
// xw: fused prep + x->bf16 convert. Blocks 0..383: W^T transpose (as prep).
// Blocks 384..2431: convert 8192 x elems each, fully coalesced.
// ---------------------------------------------------------------------------
__global__ __launch_bounds__(256)
void xw_kernel(const float* __restrict__ x,
               const float* __restrict__ Wq, const float* __restrict__ Wk,
               const float* __restrict__ Wv, u16* __restrict__ Wt,
               u16* __restrict__ xbo)
{
    const int bid = blockIdx.x;
    const int tid = threadIdx.x;
    if (bid < 384) {
        int id = bid * 256 + tid;
        int w   = id >> 15;
        int rem = id & 32767;
        int c   = rem >> 5;
        int n4  = (rem & 31) << 2;
        const float* W = (w == 0) ? Wq : (w == 1) ? Wk : Wv;
        float4 v = *(const float4*)(W + (size_t)c * Kn + n4);
        u16* dst = Wt + (size_t)w * Kn * Cn;
        dst[(size_t)(n4 + 0) * Cn + c] = f2b(v.x);
        dst[(size_t)(n4 + 1) * Cn + c] = f2b(v.y);
        dst[(size_t)(n4 + 2) * Cn + c] = f2b(v.z);
        dst[(size_t)(n4 + 3) * Cn + c] = f2b(v.w);
    } else {
        const int id = bid - 384;                   // 0..2047
        const float* src = x + (size_t)id * 8192;
        u16* dst = xbo + (size_t)id * 8192;
        #pragma unroll
        for (int it = 0; it < 4; ++it) {
            const float* s = src + it * 2048 + tid * 8;
            float4 a = *(const float4*)(s);
            float4 b = *(const float4*)(s + 4);
            u32 p0 = (u32)f2b(a.x) | ((u32)f2b(a.y) << 16);
            u32 p1 = (u32)f2b(a.z) | ((u32)f2b(a.w) << 16);
            u32 p2 = (u32)f2b(b.x) | ((u32)f2b(b.y) << 16);
            u32 p3 = (u32)f2b(b.z) | ((u32)f2b(b.w) << 16);
            uint4 pk = {p0, p1, p2, p3};
            *(uint4*)(dst + it * 2048 + tid * 8) = pk;
        }
    }
}

// ---------------------------------------------------------------------------
// proj (fallback): 128x128 tile, in-loop fp32->bf16 conversion. Known-good R4.
// ---------------------------------------------------------------------------
__global__ __launch_bounds__(256)
void proj_kernel(const float* __restrict__ x, const u16* __restrict__ Wt,
                 u16* __restrict__ qkv)
{
    const int bid = blockIdx.x;
    const int g8  = bid >> 3, xr = bid & 7;
    const int w   = g8 % 3;
    const int rt  = (g8 / 3) * 8 + xr;
    const u16* wtg = Wt + (size_t)w * Kn * Cn;
    u16* outp = qkv + (size_t)w * Bn * Tn * Kn;
    const int row0 = rt * 128;
    const int tid  = threadIdx.x;
    const int lane = tid & 63;
    const int wid  = tid >> 6;
    const int l15  = lane & 15, lh = lane >> 4;
    const int wm0 = (wid >> 1) * 64, wn0 = (wid & 1) * 64;

    __shared__ u16 xs[128][72];
    __shared__ u16 wt[128][72];

    f32x4 acc[4][4];
    #pragma unroll
    for (int i = 0; i < 4; ++i)
        #pragma unroll
        for (int j = 0; j < 4; ++j) acc[i][j] = (f32x4){0.f, 0.f, 0.f, 0.f};

    for (int kk = 0; kk < Cn; kk += 64) {
        __syncthreads();
        #pragma unroll
        for (int i = 0; i < 8; ++i) {
            int idx = tid + i * 256;
            int r = idx >> 4, c4 = (idx & 15) << 2;
            float4 xv = *(const float4*)(x + (size_t)(row0 + r) * Cn + kk + c4);
            ushort4 pk = { f2b(xv.x), f2b(xv.y), f2b(xv.z), f2b(xv.w) };
            *(ushort4*)&xs[r][c4] = pk;
        }
        #pragma unroll
        for (int i = 0; i < 4; ++i) {
            int idx = tid + i * 256;
            int n = idx >> 3, c8 = (idx & 7) << 3;
            uint4 wv = *(const uint4*)(wtg + (size_t)n * Cn + kk + c8);
            *(uint4*)&wt[n][c8] = wv;
        }
        __syncthreads();
        #pragma unroll
        for (int kc = 0; kc < 2; ++kc) {
            const int coff = kc * 32 + lh * 8;
            short8 af[4], bf[4];
            #pragma unroll
            for (int mg = 0; mg < 4; ++mg)
                af[mg] = *(const short8*)&xs[wm0 + mg * 16 + l15][coff];
            #pragma unroll
            for (int ng = 0; ng < 4; ++ng)
                bf[ng] = *(const short8*)&wt[wn0 + ng * 16 + l15][coff];
            #pragma unroll
            for (int mg = 0; mg < 4; ++mg)
                #pragma unroll
                for (int ng = 0; ng < 4; ++ng)
                    acc[mg][ng] = __builtin_amdgcn_mfma_f32_16x16x32_bf16(
                        af[mg], bf[ng], acc[mg][ng], 0, 0, 0);
        }
    }
    #pragma unroll
    for (int mg = 0; mg < 4; ++mg)
        #pragma unroll
        for (int ng = 0; ng < 4; ++ng)
            #pragma unroll
            for (int r = 0; r < 4; ++r) {
                int m = row0 + wm0 + mg * 16 + lh * 4 + r;
                int n = wn0 + ng * 16 + l15;
                outp[(size_t)m * Kn + n] = f2b(acc[mg][ng][r]);
            }
}

// ---------------------------------------------------------------------------
// proj2: bf16-x path. 64x128 tile -> 768 blocks (3/CU). Both operands staged
// via global_load_lds (16B) with pre-swizzled source; double-buffered;
// 2-barrier m97 loop. LDS 48KB.
// ---------------------------------------------------------------------------
__global__ __launch_bounds__(256)
void proj2_kernel(const u16* __restrict__ xb, const u16* __restrict__ Wt,
                  u16* __restrict__ qkv)
{
    const int bid = blockIdx.x;
    const int w   = bid % 3;
    const int rt  = bid / 3;                       // 0..255
    const u16* wtg = Wt + (size_t)w * Kn * Cn;     // [128 n][1024 c]
    u16* outp = qkv + (size_t)w * Bn * Tn * Kn;
    const int row0 = rt * 64;
    const int tid  = threadIdx.x;
    const int lane = tid & 63;
    const int wid  = tid >> 6;
    const int l15  = lane & 15, lh = lane >> 4;
    const int m0 = (wid >> 1) * 32, n0 = (wid & 1) * 64;

    // xs: 2 x [64][64] at 0 / 4096 (u16); wsb: 2 x [128][64] at 8192 / 16384.
    __shared__ u16 lds[24576];

    auto stage = [&](int kk, int buf) {
        #pragma unroll
        for (int i = 0; i < 2; ++i) {
            int u = tid + i * 256;                 // 0..511
            int row = u >> 3, c8 = u & 7;
            load_lds16(xb + (size_t)(row0 + row) * Cn + kk + ((c8 ^ (row & 7)) << 3),
                       lds + buf * 4096 + u * 8);
        }
        #pragma unroll
        for (int i = 0; i < 4; ++i) {
            int u = tid + i * 256;                 // 0..1023
            int n = u >> 3, c8 = u & 7;
            load_lds16(wtg + (size_t)n * Cn + kk + ((c8 ^ (n & 7)) << 3),
                       lds + 8192 + buf * 8192 + u * 8);
        }
    };

    f32x4 acc[2][4];
    #pragma unroll
    for (int i = 0; i < 2; ++i)
        #pragma unroll
        for (int j = 0; j < 4; ++j) acc[i][j] = (f32x4){0.f, 0.f, 0.f, 0.f};

    stage(0, 0);
    for (int step = 0; step < 16; ++step) {
        const int buf = step & 1;
        __syncthreads();                           // drains vmcnt of stage(buf)
        if (step < 15) stage((step + 1) * 64, buf ^ 1);
        const u16* Xb = lds + buf * 4096;
        const u16* Wb = lds + 8192 + buf * 8192;
        #pragma unroll
        for (int kc = 0; kc < 2; ++kc) {
            short8 af[2], bf[4];
            #pragma unroll
            for (int mg = 0; mg < 2; ++mg) {
                int row = m0 + mg * 16 + l15;
                int ch  = (kc * 4 + lh) ^ (row & 7);
                af[mg] = *(const short8*)(Xb + row * 64 + ch * 8);
            }
            #pragma unroll
            for (int ng = 0; ng < 4; ++ng) {
                int n  = n0 + ng * 16 + l15;
                int ch = (kc * 4 + lh) ^ (n & 7);
                bf[ng] = *(const short8*)(Wb + n * 64 + ch * 8);
            }
            #pragma unroll
            for (int mg = 0; mg < 2; ++mg)
                #pragma unroll
                for (int ng = 0; ng < 4; ++ng)
                    acc[mg][ng] = __builtin_amdgcn_mfma_f32_16x16x32_bf16(
                        af[mg], bf[ng], acc[mg][ng], 0, 0, 0);
        }
    }
    #pragma unroll
    for (int mg = 0; mg < 2; ++mg)
        #pragma unroll
        for (int ng = 0; ng < 4; ++ng)
            #pragma unroll
            for (int r = 0; r < 4; ++r) {
                int m = row0 + m0 + mg * 16 + lh * 4 + r;
                int n = n0 + ng * 16 + l15;
                outp[(size_t)m * Kn + n] = f2b(acc[mg][ng][r]);
            }
}

// ---------------------------------------------------------------------------
// attn: causal flash, split-s equal-work blocks (unchanged from R4).
// ---------------------------------------------------------------------------
__device__ const int g_job_qi[32] = {0, 1,1, 2,2,2, 3,3,3,3, 4,4,4,4,
                                     5,5,5,5,5, 6,6,6,6,6,6, 7,7,7,7,7,7,7};
__device__ const int g_sup_b[32] = {0, 0,4, 0,4,8, 0,4,8,12, 0,5,10,15,
                                    0,4,9,14,19, 0,4,9,14,18,23, 0,4,9,13,18,22,27};
__device__ const int g_sup_e[32] = {4, 4,8, 4,8,12, 4,8,12,16, 5,10,15,20,
                                    4,9,14,19,24, 4,9,14,18,23,28, 4,9,13,18,22,27,32};

__global__ __launch_bounds__(512, 2)
void attn_kernel(const u16* __restrict__ qg_, const u16* __restrict__ kg_,
                 const u16* __restrict__ vg_, u16* __restrict__ pO,
                 float* __restrict__ pM, float* __restrict__ pL)
{
    const int b   = blockIdx.x;
    const int job = blockIdx.y;
    const int qi  = g_job_qi[job];
    const int sb  = g_sup_b[job], se = g_sup_e[job];

    const u16* qw = qg_ + (size_t)b * Tn * Kn;
    const u16* kw = kg_ + (size_t)b * Tn * Kn;
    const u16* vw = vg_ + (size_t)b * Tn * Kn;

    const int tid  = threadIdx.x;
    const int lane = tid & 63;
    const int wid  = tid >> 6;
    const int l15  = lane & 15, lh = lane >> 4;

    const int q0 = qi * 256 + wid * 32;
    const int qmax_w = q0 + 31;

    __shared__ u16 lds[32768];

    short8 qf[2][4];
    #pragma unroll
    for (int g = 0; g < 2; ++g)
        #pragma unroll
        for (int kc = 0; kc < 4; ++kc)
            qf[g][kc] = *(const short8*)(qw + (size_t)(q0 + g * 16 + l15) * Kn
                                         + kc * 32 + lh * 8);

    f32x4 acc[8][2];
    #pragma unroll
    for (int dt = 0; dt < 8; ++dt)
        #pragma unroll
        for (int g = 0; g < 2; ++g) acc[dt][g] = (f32x4){0.f, 0.f, 0.f, 0.f};
    float m_g[2] = {NEGINF, NEGINF}, l_g[2] = {0.f, 0.f};

    const float scale = 0.08838834764831843f;

    auto stageK = [&](int sup, int buf) {
        const u16* src = kw + (size_t)sup * 64 * Kn;
        u16* dst = lds + buf * 8192;
        #pragma unroll
        for (int i = 0; i < 2; ++i) {
            int u = wid * 128 + i * 64 + lane;
            int row = u >> 4;
            int c16 = (u & 15) ^ (row & 7);
            load_lds16(src + (size_t)row * Kn + c16 * 8,
                       dst + (size_t)(wid * 128 + i * 64) * 8);
        }
    };
    auto loadV = [&](int sup, uint4* vr) {
        const u16* src = vw + (size_t)sup * 64 * Kn;
        #pragma unroll
        for (int r = 0; r < 2; ++r) {
            int s  = tid & 63;
            int u8 = (tid >> 6) + 8 * r;
            vr[r] = *(const uint4*)(src + (size_t)s * Kn + u8 * 8);
        }
    };
    auto writeV = [&](int buf, const uint4* vr) {
        u16* dst = lds + 16384 + buf * 8192;
        #pragma unroll
        for (int r = 0; r < 2; ++r) {
            int s  = tid & 63;
            int u8 = (tid >> 6) + 8 * r;
            const u16* e = (const u16*)&vr[r];
            #pragma unroll
            for (int j = 0; j < 8; ++j) {
                int d = u8 * 8 + j;
                dst[d * 64 + (((s >> 3) ^ j) << 3) + (s & 7)] = e[j];
            }
        }
    };

    uint4 vreg[2];
    stageK(sb, 0);
    loadV(sb, vreg);
    writeV(0, vreg);

    for (int sup = sb; sup < se; ++sup) {
        const int cur = (sup - sb) & 1;
        __syncthreads();
        const bool have_next = (sup + 1 < se);
        if (have_next) {
            stageK(sup + 1, cur ^ 1);
            loadV(sup + 1, vreg);
        }
        if (sup * 64 <= qmax_w) {
            const u16* Kb = lds + cur * 8192;
            const u16* Vb = lds + 16384 + cur * 8192;
            f32x4 sf[4][2];
            #pragma unroll
            for (int mt = 0; mt < 4; ++mt)
                #pragma unroll
                for (int g = 0; g < 2; ++g) sf[mt][g] = (f32x4){0.f,0.f,0.f,0.f};
            #pragma unroll
            for (int kc = 0; kc < 4; ++kc) {
                short8 a[4];
                #pragma unroll
                for (int mt = 0; mt < 4; ++mt) {
                    int row = mt * 16 + l15;
                    int ch  = (kc * 4 + lh) ^ (row & 7);
                    a[mt] = *(const short8*)(Kb + row * 128 + ch * 8);
                }
                #pragma unroll
                for (int mt = 0; mt < 4; ++mt)
                    #pragma unroll
                    for (int g = 0; g < 2; ++g)
                        sf[mt][g] = __builtin_amdgcn_mfma_f32_16x16x32_bf16(
                            a[mt], qf[g][kc], sf[mt][g], 0, 0, 0);
            }
            const int sbase = sup * 64;
            u32 upk[2][4][2];
            float alpha_g[2];
            #pragma unroll
            for (int g = 0; g < 2; ++g) {
                const int qg = q0 + g * 16 + l15;
                float pv[16];
                float pm = NEGINF;
                #pragma unroll
                for (int mt = 0; mt < 4; ++mt)
                    #pragma unroll
                    for (int r = 0; r < 4; ++r) {
                        int sg = sbase + mt * 16 + lh * 4 + r;
                        float vv = sf[mt][g][r] * scale;
                        vv = (sg > qg) ? NEGINF : vv;
                        pv[mt * 4 + r] = vv;
                        pm = fmaxf(pm, vv);
                    }
                pm = fmaxf(pm, __shfl_xor(pm, 16));
                pm = fmaxf(pm, __shfl_xor(pm, 32));
                float mn  = fmaxf(m_g[g], pm);
                float mns = (mn == NEGINF) ? 0.f : mn;
                float al  = __expf(m_g[g] - mns);
                m_g[g] = mn;
                alpha_g[g] = al;
                float ps = 0.f;
                #pragma unroll
                for (int i = 0; i < 16; ++i) { pv[i] = __expf(pv[i] - mns); ps += pv[i]; }
                ps += __shfl_xor(ps, 16);
                ps += __shfl_xor(ps, 32);
                l_g[g] = l_g[g] * al + ps;
                #pragma unroll
                for (int mt = 0; mt < 4; ++mt)
                    #pragma unroll
                    for (int h = 0; h < 2; ++h)
                        upk[g][mt][h] = (u32)f2b(pv[mt * 4 + 2 * h])
                                      | ((u32)f2b(pv[mt * 4 + 2 * h + 1]) << 16);
            }
            #pragma unroll
            for (int dt = 0; dt < 8; ++dt)
                #pragma unroll
                for (int g = 0; g < 2; ++g)
                    acc[dt][g] *= alpha_g[g];
            #pragma unroll
            for (int ks = 0; ks < 2; ++ks) {
                short8 pf[2];
                #pragma unroll
                for (int g = 0; g < 2; ++g) {
                    union { u32 w[4]; short8 v; } uu;
                    #pragma unroll
                    for (int hp = 0; hp < 4; ++hp) {
                        int srcLane = l15 + 16 * ((lh & 1) * 2 + (hp >> 1));
                        u32 vA = __shfl(upk[g][2 * ks][hp & 1], srcLane, 64);
                        u32 vB = __shfl(upk[g][2 * ks + 1][hp & 1], srcLane, 64);
                        uu.w[hp] = (lh < 2) ? vA : vB;
                    }
                    pf[g] = uu.v;
                }
                #pragma unroll
                for (int dt = 0; dt < 8; ++dt) {
                    int d  = dt * 16 + l15;
                    int ch = (ks * 4 + lh) ^ (d & 7);
                    short8 av = *(const short8*)(Vb + d * 64 + ch * 8);
                    #pragma unroll
                    for (int g = 0; g < 2; ++g)
                        acc[dt][g] = __builtin_amdgcn_mfma_f32_16x16x32_bf16(
                            av, pf[g], acc[dt][g], 0, 0, 0);
                }
            }
        }
        if (have_next) writeV(cur ^ 1, vreg);
    }

    const size_t slotrow = ((size_t)b * 32 + job) * 256 + wid * 32;
    #pragma unroll
    for (int g = 0; g < 2; ++g) {
        size_t row = slotrow + g * 16 + l15;
        #pragma unroll
        for (int dt = 0; dt < 8; ++dt) {
            ushort4 o = { f2b(acc[dt][g][0]), f2b(acc[dt][g][1]),
                          f2b(acc[dt][g][2]), f2b(acc[dt][g][3]) };
            *(ushort4*)(pO + row * 128 + dt * 16 + lh * 4) = o;
        }
        if (lh == 0) {
            pM[row] = m_g[g];
            pL[row] = l_g[g];
        }
    }
}

// ---------------------------------------------------------------------------
// merge v2 (unchanged from R4).
// ---------------------------------------------------------------------------
__device__ const int g_cnt[8] = {1, 2, 3, 4, 4, 5, 6, 7};
__device__ const int g_s0[8]  = {0, 1, 3, 6, 10, 14, 19, 25};

__global__ __launch_bounds__(256)
void merge_kernel(const u16* __restrict__ pO, const float* __restrict__ pM,
                  const float* __restrict__ pL, float* __restrict__ out)
{
    const int bid = blockIdx.x;
    const int b   = bid >> 8;
    const int rem = bid & 255;
    const int qi  = rem >> 5;
    const int rg  = rem & 31;
    const int c = g_cnt[qi], s0 = g_s0[qi];
    const int tid = threadIdx.x;
    const int r8 = tid >> 5;
    const int dg = tid & 31;

    const int row = rg * 8 + r8;
    const size_t base = ((size_t)b * 32 + s0) * 256 + row;

    float mv[8];
    float M = NEGINF;
    #pragma unroll
    for (int i = 0; i < 8; ++i)
        if (i < c) { mv[i] = pM[base + (size_t)i * 256]; M = fmaxf(M, mv[i]); }
    float L = 0.f, w[8];
    #pragma unroll
    for (int i = 0; i < 8; ++i)
        if (i < c) {
            float e = __expf(mv[i] - M);
            L += pL[base + (size_t)i * 256] * e;
            w[i] = e;
        }
    const float invL = 1.f / L;

    float4 o = {0.f, 0.f, 0.f, 0.f};
    #pragma unroll
    for (int i = 0; i < 8; ++i)
        if (i < c) {
            ushort4 p = *(const ushort4*)(pO + (base + (size_t)i * 256) * 128 + dg * 4);
            float wi = w[i] * invL;
            o.x = fmaf(wi, b2f(p.x), o.x);
            o.y = fmaf(wi, b2f(p.y), o.y);
            o.z = fmaf(wi, b2f(p.z), o.z);
            o.w = fmaf(wi, b2f(p.w), o.w);
        }
    *(float4*)(out + ((size_t)b * Tn + qi * 256 + row) * Kn + dg * 4) = o;
}

// ---------------------------------------------------------------------------
extern "C" void kernel_launch(void* const* d_in, const int* in_sizes, int n_in,
                              void* d_out, int out_size, void* d_ws, size_t ws_size,
                              hipStream_t stream)
{
    const float* x  = (const float*)d_in[0];
    const float* Wq = (const float*)d_in[1];
    const float* Wk = (const float*)d_in[2];
    const float* Wv = (const float*)d_in[3];
    float* out = (float*)d_out;

    u16* ws = (u16*)d_ws;
    const size_t btk = (size_t)Bn * Tn * Kn;       // 2,097,152
    u16* q  = ws;
    u16* k  = ws + btk;
    u16* v  = ws + 2 * btk;
    u16* Wt = ws + 3 * btk;                        // 393216 u16

    const size_t X0   = 3 * btk + 393216;          // 6,684,672 u16
    const size_t NEED = (X0 + (size_t)16777216) * 2;  // 46,923,776 bytes

    if (ws_size >= NEED) {
        // fast path: xb at X0; pO/pM/pL alias xb (live only after proj2)
        u16* xb = ws + X0;
        u16* pO = ws + X0;
        float* pM = (float*)(pO + (size_t)8388608);
        float* pL = pM + 65536;
        xw_kernel<<<2432, 256, 0, stream>>>(x, Wq, Wk, Wv, Wt, xb);
        proj2_kernel<<<768, 256, 0, stream>>>(xb, Wt, ws);
        attn_kernel<<<dim3(Bn, 32), 512, 0, stream>>>(q, k, v, pO, pM, pL);
        merge_kernel<<<2048, 256, 0, stream>>>(pO, pM, pL, out);
    } else {
        // fallback: R4 layout (30.7 MB)
        u16* pO = ws + X0;
        float* pM = (float*)(pO + (size_t)8388608);
        float* pL = pM + 65536;
        prep_kernel<<<384, 256, 0, stream>>>(Wq, Wk, Wv, Wt);
        proj_kernel<<<384, 256, 0, stream>>>(x, Wt, ws);
        attn_kernel<<<dim3(Bn, 32), 512, 0, stream>>>(q, k, v, pO, pM, pL);
        merge_kernel<<<2048, 256, 0, stream>>>(pO, pM, pL, out);
    }
}

// Round 6
// 71.805 us; speedup vs baseline: 1.0600x; 1.0600x over previous
//
#include <hip/hip_runtime.h>
#include <cmath>

#define Bn 8
#define Tn 2048
#define Cn 1024
#define Kn 128

typedef __attribute__((ext_vector_type(8))) short short8;
typedef __attribute__((ext_vector_type(4))) float f32x4;
typedef unsigned short u16;
typedef unsigned int u32;

#define NEGINF (-__builtin_huge_valf())

__device__ __forceinline__ u16 f2b(float f) {
    u32 u = __float_as_uint(f);
    u32 r = (u + 0x7FFFu + ((u >> 16) & 1u)) >> 16;
    return (u16)r;
}
__device__ __forceinline__ float b2f(u16 v) {
    u32 u = ((u32)v) << 16;
    return __uint_as_float(u);
}
// packed fp32x2 -> bf16x2 (lo -> [15:0], hi -> [31:16]), RNE. No builtin on gfx950.
__device__ __forceinline__ u32 cvtpk(float lo, float hi) {
    u32 r;
    asm("v_cvt_pk_bf16_f32 %0, %1, %2" : "=v"(r) : "v"(lo), "v"(hi));
    return r;
}

__device__ __forceinline__ void load_lds16(const u16* g, u16* l) {
    __builtin_amdgcn_global_load_lds(
        (const __attribute__((address_space(1))) u32*)(g),
        (__attribute__((address_space(3))) u32*)(l), 16, 0, 0);
}

// ---------------------------------------------------------------------------
// prep: W [1024 c][128 n] fp32 -> W^T bf16 [3][128 n][1024 c]
// ---------------------------------------------------------------------------
__global__ __launch_bounds__(256)
void prep_kernel(const float* __restrict__ Wq, const float* __restrict__ Wk,
                 const float* __restrict__ Wv, u16* __restrict__ Wt)
{
    int id = blockIdx.x * 256 + threadIdx.x;
    int w   = id >> 15;
    int rem = id & 32767;
    int c   = rem >> 5;
    int n4  = (rem & 31) << 2;
    const float* W = (w == 0) ? Wq : (w == 1) ? Wk : Wv;
    float4 v = *(const float4*)(W + (size_t)c * Kn + n4);
    u16* dst = Wt + (size_t)w * Kn * Cn;
    dst[(size_t)(n4 + 0) * Cn + c] = f2b(v.x);
    dst[(size_t)(n4 + 1) * Cn + c] = f2b(v.y);
    dst[(size_t)(n4 + 2) * Cn + c] = f2b(v.z);
    dst[(size_t)(n4 + 3) * Cn + c] = f2b(v.w);
}

// ---------------------------------------------------------------------------
// proj3: qkv[w] = x @ W[w]. 128x128 tile, 4 waves x (64x64, acc 4x4), BK=64.
// x: fp32 -> regs -> v_cvt_pk_bf16_f32 -> swizzled ds_write (issue-early /
// write-late). W^T: global_load_lds 16B, source pre-swizzled. Double-buffered,
// 64KB LDS (2 blocks/CU). Grid 384: w-triples adjacent on one XCD (x L2 reuse).
// ---------------------------------------------------------------------------
__global__ __launch_bounds__(256)
void proj3_kernel(const float* __restrict__ x, const u16* __restrict__ Wt,
                  u16* __restrict__ qkv)
{
    const int bid = blockIdx.x;
    const int g8  = bid >> 3, xr = bid & 7;
    const int w   = g8 % 3;
    const int rt  = (g8 / 3) * 8 + xr;            // 0..127
    const u16* wtg = Wt + (size_t)w * Kn * Cn;    // [128 n][1024 c]
    u16* outp = qkv + (size_t)w * Bn * Tn * Kn;
    const int row0 = rt * 128;
    const int tid  = threadIdx.x;
    const int lane = tid & 63;
    const int wid  = tid >> 6;
    const int l15  = lane & 15, lh = lane >> 4;
    const int m0 = (wid >> 1) * 64, n0 = (wid & 1) * 64;

    // u16 units: xs0 @0, xs1 @8192, wt0 @16384, wt1 @24576 (each 128x64).
    __shared__ u16 lds[32768];

    auto stageW = [&](int kk, int buf) {
        #pragma unroll
        for (int i = 0; i < 4; ++i) {
            int u = tid + i * 256;                 // 0..1023 16B-chunks
            int n = u >> 3, c8 = u & 7;
            load_lds16(wtg + (size_t)n * Cn + kk + ((c8 ^ (n & 7)) << 3),
                       lds + 16384 + buf * 8192 + u * 8);
        }
    };
    auto loadX = [&](int kk, float4* xr4) {
        #pragma unroll
        for (int i = 0; i < 4; ++i) {
            int u = tid + i * 256;                 // 0..1023 8-float chunks
            int r = u >> 3, c8 = u & 7;
            const float* s = x + (size_t)(row0 + r) * Cn + kk + c8 * 8;
            xr4[2 * i]     = *(const float4*)(s);
            xr4[2 * i + 1] = *(const float4*)(s + 4);
        }
    };
    auto writeX = [&](int buf, const float4* xr4) {
        u16* dst = lds + buf * 8192;
        #pragma unroll
        for (int i = 0; i < 4; ++i) {
            int u = tid + i * 256;
            int r = u >> 3, c8 = u & 7;
            uint4 pk;
            pk.x = cvtpk(xr4[2 * i].x,     xr4[2 * i].y);
            pk.y = cvtpk(xr4[2 * i].z,     xr4[2 * i].w);
            pk.z = cvtpk(xr4[2 * i + 1].x, xr4[2 * i + 1].y);
            pk.w = cvtpk(xr4[2 * i + 1].z, xr4[2 * i + 1].w);
            *(uint4*)(dst + r * 64 + ((c8 ^ (r & 7)) << 3)) = pk;
        }
    };

    f32x4 acc[4][4];
    #pragma unroll
    for (int i = 0; i < 4; ++i)
        #pragma unroll
        for (int j = 0; j < 4; ++j) acc[i][j] = (f32x4){0.f, 0.f, 0.f, 0.f};

    float4 xcur[8];
    loadX(0, xcur);
    stageW(0, 0);
    writeX(0, xcur);

    for (int step = 0; step < 16; ++step) {
        const int buf = step & 1;
        __syncthreads();                           // drains vmcnt + lgkmcnt
        const bool nxt = (step < 15);
        float4 xnext[8];
        if (nxt) {
            loadX((step + 1) * 64, xnext);         // issue early (T14)
            stageW((step + 1) * 64, buf ^ 1);      // fire-and-forget
        }
        const u16* Xb = lds + buf * 8192;
        const u16* Wb = lds + 16384 + buf * 8192;
        #pragma unroll
        for (int kc = 0; kc < 2; ++kc) {
            short8 af[4], bf[4];
            #pragma unroll
            for (int mg = 0; mg < 4; ++mg) {
                int row = m0 + mg * 16 + l15;
                int ch  = (kc * 4 + lh) ^ (row & 7);
                af[mg] = *(const short8*)(Xb + row * 64 + ch * 8);
            }
            #pragma unroll
            for (int ng = 0; ng < 4; ++ng) {
                int n  = n0 + ng * 16 + l15;
                int ch = (kc * 4 + lh) ^ (n & 7);
                bf[ng] = *(const short8*)(Wb + n * 64 + ch * 8);
            }
            #pragma unroll
            for (int mg = 0; mg < 4; ++mg)
                #pragma unroll
                for (int ng = 0; ng < 4; ++ng)
                    acc[mg][ng] = __builtin_amdgcn_mfma_f32_16x16x32_bf16(
                        af[mg], bf[ng], acc[mg][ng], 0, 0, 0);
        }
        if (nxt) writeX(buf ^ 1, xnext);           // write late, pre-barrier
    }

    #pragma unroll
    for (int mg = 0; mg < 4; ++mg)
        #pragma unroll
        for (int ng = 0; ng < 4; ++ng)
            #pragma unroll
            for (int r = 0; r < 4; ++r) {
                int m = row0 + m0 + mg * 16 + lh * 4 + r;
                int n = n0 + ng * 16 + l15;
                outp[(size_t)m * Kn + n] = f2b(acc[mg][ng][r]);
            }
}

// ---------------------------------------------------------------------------
// attn: causal flash, split-s equal-work blocks (unchanged from R4).
// ---------------------------------------------------------------------------
__device__ const int g_job_qi[32] = {0, 1,1, 2,2,2, 3,3,3,3, 4,4,4,4,
                                     5,5,5,5,5, 6,6,6,6,6,6, 7,7,7,7,7,7,7};
__device__ const int g_sup_b[32] = {0, 0,4, 0,4,8, 0,4,8,12, 0,5,10,15,
                                    0,4,9,14,19, 0,4,9,14,18,23, 0,4,9,13,18,22,27};
__device__ const int g_sup_e[32] = {4, 4,8, 4,8,12, 4,8,12,16, 5,10,15,20,
                                    4,9,14,19,24, 4,9,14,18,23,28, 4,9,13,18,22,27,32};

__global__ __launch_bounds__(512, 2)
void attn_kernel(const u16* __restrict__ qg_, const u16* __restrict__ kg_,
                 const u16* __restrict__ vg_, u16* __restrict__ pO,
                 float* __restrict__ pM, float* __restrict__ pL)
{
    const int b   = blockIdx.x;
    const int job = blockIdx.y;
    const int qi  = g_job_qi[job];
    const int sb  = g_sup_b[job], se = g_sup_e[job];

    const u16* qw = qg_ + (size_t)b * Tn * Kn;
    const u16* kw = kg_ + (size_t)b * Tn * Kn;
    const u16* vw = vg_ + (size_t)b * Tn * Kn;

    const int tid  = threadIdx.x;
    const int lane = tid & 63;
    const int wid  = tid >> 6;
    const int l15  = lane & 15, lh = lane >> 4;

    const int q0 = qi * 256 + wid * 32;
    const int qmax_w = q0 + 31;

    __shared__ u16 lds[32768];

    short8 qf[2][4];
    #pragma unroll
    for (int g = 0; g < 2; ++g)
        #pragma unroll
        for (int kc = 0; kc < 4; ++kc)
            qf[g][kc] = *(const short8*)(qw + (size_t)(q0 + g * 16 + l15) * Kn
                                         + kc * 32 + lh * 8);

    f32x4 acc[8][2];
    #pragma unroll
    for (int dt = 0; dt < 8; ++dt)
        #pragma unroll
        for (int g = 0; g < 2; ++g) acc[dt][g] = (f32x4){0.f, 0.f, 0.f, 0.f};
    float m_g[2] = {NEGINF, NEGINF}, l_g[2] = {0.f, 0.f};

    const float scale = 0.08838834764831843f;

    auto stageK = [&](int sup, int buf) {
        const u16* src = kw + (size_t)sup * 64 * Kn;
        u16* dst = lds + buf * 8192;
        #pragma unroll
        for (int i = 0; i < 2; ++i) {
            int u = wid * 128 + i * 64 + lane;
            int row = u >> 4;
            int c16 = (u & 15) ^ (row & 7);
            load_lds16(src + (size_t)row * Kn + c16 * 8,
                       dst + (size_t)(wid * 128 + i * 64) * 8);
        }
    };
    auto loadV = [&](int sup, uint4* vr) {
        const u16* src = vw + (size_t)sup * 64 * Kn;
        #pragma unroll
        for (int r = 0; r < 2; ++r) {
            int s  = tid & 63;
            int u8 = (tid >> 6) + 8 * r;
            vr[r] = *(const uint4*)(src + (size_t)s * Kn + u8 * 8);
        }
    };
    auto writeV = [&](int buf, const uint4* vr) {
        u16* dst = lds + 16384 + buf * 8192;
        #pragma unroll
        for (int r = 0; r < 2; ++r) {
            int s  = tid & 63;
            int u8 = (tid >> 6) + 8 * r;
            const u16* e = (const u16*)&vr[r];
            #pragma unroll
            for (int j = 0; j < 8; ++j) {
                int d = u8 * 8 + j;
                dst[d * 64 + (((s >> 3) ^ j) << 3) + (s & 7)] = e[j];
            }
        }
    };

    uint4 vreg[2];
    stageK(sb, 0);
    loadV(sb, vreg);
    writeV(0, vreg);

    for (int sup = sb; sup < se; ++sup) {
        const int cur = (sup - sb) & 1;
        __syncthreads();
        const bool have_next = (sup + 1 < se);
        if (have_next) {
            stageK(sup + 1, cur ^ 1);
            loadV(sup + 1, vreg);
        }
        if (sup * 64 <= qmax_w) {
            const u16* Kb = lds + cur * 8192;
            const u16* Vb = lds + 16384 + cur * 8192;
            f32x4 sf[4][2];
            #pragma unroll
            for (int mt = 0; mt < 4; ++mt)
                #pragma unroll
                for (int g = 0; g < 2; ++g) sf[mt][g] = (f32x4){0.f,0.f,0.f,0.f};
            #pragma unroll
            for (int kc = 0; kc < 4; ++kc) {
                short8 a[4];
                #pragma unroll
                for (int mt = 0; mt < 4; ++mt) {
                    int row = mt * 16 + l15;
                    int ch  = (kc * 4 + lh) ^ (row & 7);
                    a[mt] = *(const short8*)(Kb + row * 128 + ch * 8);
                }
                #pragma unroll
                for (int mt = 0; mt < 4; ++mt)
                    #pragma unroll
                    for (int g = 0; g < 2; ++g)
                        sf[mt][g] = __builtin_amdgcn_mfma_f32_16x16x32_bf16(
                            a[mt], qf[g][kc], sf[mt][g], 0, 0, 0);
            }
            const int sbase = sup * 64;
            u32 upk[2][4][2];
            float alpha_g[2];
            #pragma unroll
            for (int g = 0; g < 2; ++g) {
                const int qg = q0 + g * 16 + l15;
                float pv[16];
                float pm = NEGINF;
                #pragma unroll
                for (int mt = 0; mt < 4; ++mt)
                    #pragma unroll
                    for (int r = 0; r < 4; ++r) {
                        int sg = sbase + mt * 16 + lh * 4 + r;
                        float vv = sf[mt][g][r] * scale;
                        vv = (sg > qg) ? NEGINF : vv;
                        pv[mt * 4 + r] = vv;
                        pm = fmaxf(pm, vv);
                    }
                pm = fmaxf(pm, __shfl_xor(pm, 16));
                pm = fmaxf(pm, __shfl_xor(pm, 32));
                float mn  = fmaxf(m_g[g], pm);
                float mns = (mn == NEGINF) ? 0.f : mn;
                float al  = __expf(m_g[g] - mns);
                m_g[g] = mn;
                alpha_g[g] = al;
                float ps = 0.f;
                #pragma unroll
                for (int i = 0; i < 16; ++i) { pv[i] = __expf(pv[i] - mns); ps += pv[i]; }
                ps += __shfl_xor(ps, 16);
                ps += __shfl_xor(ps, 32);
                l_g[g] = l_g[g] * al + ps;
                #pragma unroll
                for (int mt = 0; mt < 4; ++mt)
                    #pragma unroll
                    for (int h = 0; h < 2; ++h)
                        upk[g][mt][h] = (u32)f2b(pv[mt * 4 + 2 * h])
                                      | ((u32)f2b(pv[mt * 4 + 2 * h + 1]) << 16);
            }
            #pragma unroll
            for (int dt = 0; dt < 8; ++dt)
                #pragma unroll
                for (int g = 0; g < 2; ++g)
                    acc[dt][g] *= alpha_g[g];
            #pragma unroll
            for (int ks = 0; ks < 2; ++ks) {
                short8 pf[2];
                #pragma unroll
                for (int g = 0; g < 2; ++g) {
                    union { u32 w[4]; short8 v; } uu;
                    #pragma unroll
                    for (int hp = 0; hp < 4; ++hp) {
                        int srcLane = l15 + 16 * ((lh & 1) * 2 + (hp >> 1));
                        u32 vA = __shfl(upk[g][2 * ks][hp & 1], srcLane, 64);
                        u32 vB = __shfl(upk[g][2 * ks + 1][hp & 1], srcLane, 64);
                        uu.w[hp] = (lh < 2) ? vA : vB;
                    }
                    pf[g] = uu.v;
                }
                #pragma unroll
                for (int dt = 0; dt < 8; ++dt) {
                    int d  = dt * 16 + l15;
                    int ch = (ks * 4 + lh) ^ (d & 7);
                    short8 av = *(const short8*)(Vb + d * 64 + ch * 8);
                    #pragma unroll
                    for (int g = 0; g < 2; ++g)
                        acc[dt][g] = __builtin_amdgcn_mfma_f32_16x16x32_bf16(
                            av, pf[g], acc[dt][g], 0, 0, 0);
                }
            }
        }
        if (have_next) writeV(cur ^ 1, vreg);
    }

    const size_t slotrow = ((size_t)b * 32 + job) * 256 + wid * 32;
    #pragma unroll
    for (int g = 0; g < 2; ++g) {
        size_t row = slotrow + g * 16 + l15;
        #pragma unroll
        for (int dt = 0; dt < 8; ++dt) {
            ushort4 o = { f2b(acc[dt][g][0]), f2b(acc[dt][g][1]),
                          f2b(acc[dt][g][2]), f2b(acc[dt][g][3]) };
            *(ushort4*)(pO + row * 128 + dt * 16 + lh * 4) = o;
        }
        if (lh == 0) {
            pM[row] = m_g[g];
            pL[row] = l_g[g];
        }
    }
}

// ---------------------------------------------------------------------------
// merge v2 (unchanged from R4).
// ---------------------------------------------------------------------------
__device__ const int g_cnt[8] = {1, 2, 3, 4, 4, 5, 6, 7};
__device__ const int g_s0[8]  = {0, 1, 3, 6, 10, 14, 19, 25};

__global__ __launch_bounds__(256)
void merge_kernel(const u16* __restrict__ pO, const float* __restrict__ pM,
                  const float* __restrict__ pL, float* __restrict__ out)
{
    const int bid = blockIdx.x;
    const int b   = bid >> 8;
    const int rem = bid & 255;
    const int qi  = rem >> 5;
    const int rg  = rem & 31;
    const int c = g_cnt[qi], s0 = g_s0[qi];
    const int tid = threadIdx.x;
    const int r8 = tid >> 5;
    const int dg = tid & 31;

    const int row = rg * 8 + r8;
    const size_t base = ((size_t)b * 32 + s0) * 256 + row;

    float mv[8];
    float M = NEGINF;
    #pragma unroll
    for (int i = 0; i < 8; ++i)
        if (i < c) { mv[i] = pM[base + (size_t)i * 256]; M = fmaxf(M, mv[i]); }
    float L = 0.f, w[8];
    #pragma unroll
    for (int i = 0; i < 8; ++i)
        if (i < c) {
            float e = __expf(mv[i] - M);
            L += pL[base + (size_t)i * 256] * e;
            w[i] = e;
        }
    const float invL = 1.f / L;

    float4 o = {0.f, 0.f, 0.f, 0.f};
    #pragma unroll
    for (int i = 0; i < 8; ++i)
        if (i < c) {
            ushort4 p = *(const ushort4*)(pO + (base + (size_t)i * 256) * 128 + dg * 4);
            float wi = w[i] * invL;
            o.x = fmaf(wi, b2f(p.x), o.x);
            o.y = fmaf(wi, b2f(p.y), o.y);
            o.z = fmaf(wi, b2f(p.z), o.z);
            o.w = fmaf(wi, b2f(p.w), o.w);
        }
    *(float4*)(out + ((size_t)b * Tn + qi * 256 + row) * Kn + dg * 4) = o;
}

// ---------------------------------------------------------------------------
extern "C" void kernel_launch(void* const* d_in, const int* in_sizes, int n_in,
                              void* d_out, int out_size, void* d_ws, size_t ws_size,
                              hipStream_t stream)
{
    const float* x  = (const float*)d_in[0];
    const float* Wq = (const float*)d_in[1];
    const float* Wk = (const float*)d_in[2];
    const float* Wv = (const float*)d_in[3];
    float* out = (float*)d_out;

    u16* ws = (u16*)d_ws;
    const size_t btk = (size_t)Bn * Tn * Kn;       // 2,097,152
    u16* q  = ws;
    u16* k  = ws + btk;
    u16* v  = ws + 2 * btk;
    u16* Wt = ws + 3 * btk;                        // 393216 u16
    u16* pO = ws + 3 * btk + 393216;               // 8,388,608 u16
    float* pM = (float*)(pO + (size_t)8388608);    // 65536 f32
    float* pL = pM + 65536;                        // 65536 f32
    // total ws usage ~30.7 MB

    prep_kernel<<<384, 256, 0, stream>>>(Wq, Wk, Wv, Wt);
    proj3_kernel<<<384, 256, 0, stream>>>(x, Wt, ws);
    attn_kernel<<<dim3(Bn, 32), 512, 0, stream>>>(q, k, v, pO, pM, pL);
    merge_kernel<<<2048, 256, 0, stream>>>(pO, pM, pL, out);
}

// Round 7
// 70.734 us; speedup vs baseline: 1.0761x; 1.0151x over previous
//
#include <hip/hip_runtime.h>
#include <cmath>

#define Bn 8
#define Tn 2048
#define Cn 1024
#define Kn 128

typedef __attribute__((ext_vector_type(8))) short short8;
typedef __attribute__((ext_vector_type(4))) float f32x4;
typedef unsigned short u16;
typedef unsigned int u32;

#define NEGINF (-__builtin_huge_valf())

__device__ __forceinline__ u16 f2b(float f) {
    u32 u = __float_as_uint(f);
    u32 r = (u + 0x7FFFu + ((u >> 16) & 1u)) >> 16;
    return (u16)r;
}
__device__ __forceinline__ float b2f(u16 v) {
    u32 u = ((u32)v) << 16;
    return __uint_as_float(u);
}
// packed fp32x2 -> bf16x2 (lo -> [15:0], hi -> [31:16]), RNE.
__device__ __forceinline__ u32 cvtpk(float lo, float hi) {
    u32 r;
    asm("v_cvt_pk_bf16_f32 %0, %1, %2" : "=v"(r) : "v"(lo), "v"(hi));
    return r;
}

__device__ __forceinline__ void load_lds16(const u16* g, u16* l) {
    __builtin_amdgcn_global_load_lds(
        (const __attribute__((address_space(1))) u32*)(g),
        (__attribute__((address_space(3))) u32*)(l), 16, 0, 0);
}

// ---------------------------------------------------------------------------
// prep: W [1024 c][128 n] fp32 -> W^T bf16 [3][128 n][1024 c]
// ---------------------------------------------------------------------------
__global__ __launch_bounds__(256)
void prep_kernel(const float* __restrict__ Wq, const float* __restrict__ Wk,
                 const float* __restrict__ Wv, u16* __restrict__ Wt)
{
    int id = blockIdx.x * 256 + threadIdx.x;
    int w   = id >> 15;
    int rem = id & 32767;
    int c   = rem >> 5;
    int n4  = (rem & 31) << 2;
    const float* W = (w == 0) ? Wq : (w == 1) ? Wk : Wv;
    float4 v = *(const float4*)(W + (size_t)c * Kn + n4);
    u16* dst = Wt + (size_t)w * Kn * Cn;
    dst[(size_t)(n4 + 0) * Cn + c] = f2b(v.x);
    dst[(size_t)(n4 + 1) * Cn + c] = f2b(v.y);
    dst[(size_t)(n4 + 2) * Cn + c] = f2b(v.z);
    dst[(size_t)(n4 + 3) * Cn + c] = f2b(v.w);
}

// ---------------------------------------------------------------------------
// proj4: qkv[w] = x @ W[w]. Same tiles/addressing as proj3 (128x128, 4 waves
// x 64x64 acc4x4, BK=64) but counted-vmcnt pipeline over RAW s_barrier:
//  - x prefetched 2 steps ahead into regs (xA/xB ping-pong)
//  - W staged 1 step ahead via global_load_lds
//  - end-of-step: s_waitcnt vmcnt(8) -> x(t+2)'s 8 loads CROSS the barrier
// ---------------------------------------------------------------------------
__global__ __launch_bounds__(256)
void proj4_kernel(const float* __restrict__ x, const u16* __restrict__ Wt,
                  u16* __restrict__ qkv)
{
    const int bid = blockIdx.x;
    const int g8  = bid >> 3, xr = bid & 7;
    const int w   = g8 % 3;
    const int rt  = (g8 / 3) * 8 + xr;            // 0..127
    const u16* wtg = Wt + (size_t)w * Kn * Cn;    // [128 n][1024 c]
    u16* outp = qkv + (size_t)w * Bn * Tn * Kn;
    const int row0 = rt * 128;
    const int tid  = threadIdx.x;
    const int lane = tid & 63;
    const int wid  = tid >> 6;
    const int l15  = lane & 15, lh = lane >> 4;
    const int m0 = (wid >> 1) * 64, n0 = (wid & 1) * 64;

    // u16 units: xs0 @0, xs1 @8192, wt0 @16384, wt1 @24576 (each 128x64).
    __shared__ u16 lds[32768];

    auto stageW = [&](int kk, int buf) {
        #pragma unroll
        for (int i = 0; i < 4; ++i) {
            int u = tid + i * 256;                 // 0..1023 16B-chunks
            int n = u >> 3, c8 = u & 7;
            load_lds16(wtg + (size_t)n * Cn + kk + ((c8 ^ (n & 7)) << 3),
                       lds + 16384 + buf * 8192 + u * 8);
        }
    };
    auto loadX = [&](int kk, float4* xr4) {
        #pragma unroll
        for (int i = 0; i < 4; ++i) {
            int u = tid + i * 256;                 // 0..1023 8-float chunks
            int r = u >> 3, c8 = u & 7;
            const float* s = x + (size_t)(row0 + r) * Cn + kk + c8 * 8;
            xr4[2 * i]     = *(const float4*)(s);
            xr4[2 * i + 1] = *(const float4*)(s + 4);
        }
    };
    auto writeX = [&](int buf, const float4* xr4) {
        u16* dst = lds + buf * 8192;
        #pragma unroll
        for (int i = 0; i < 4; ++i) {
            int u = tid + i * 256;
            int r = u >> 3, c8 = u & 7;
            uint4 pk;
            pk.x = cvtpk(xr4[2 * i].x,     xr4[2 * i].y);
            pk.y = cvtpk(xr4[2 * i].z,     xr4[2 * i].w);
            pk.z = cvtpk(xr4[2 * i + 1].x, xr4[2 * i + 1].y);
            pk.w = cvtpk(xr4[2 * i + 1].z, xr4[2 * i + 1].w);
            *(uint4*)(dst + r * 64 + ((c8 ^ (r & 7)) << 3)) = pk;
        }
    };

    f32x4 acc[4][4];
    #pragma unroll
    for (int i = 0; i < 4; ++i)
        #pragma unroll
        for (int j = 0; j < 4; ++j) acc[i][j] = (f32x4){0.f, 0.f, 0.f, 0.f};

    auto compute = [&](int buf) {
        const u16* Xb = lds + buf * 8192;
        const u16* Wb = lds + 16384 + buf * 8192;
        #pragma unroll
        for (int kc = 0; kc < 2; ++kc) {
            short8 af[4], bf[4];
            #pragma unroll
            for (int mg = 0; mg < 4; ++mg) {
                int row = m0 + mg * 16 + l15;
                int ch  = (kc * 4 + lh) ^ (row & 7);
                af[mg] = *(const short8*)(Xb + row * 64 + ch * 8);
            }
            #pragma unroll
            for (int ng = 0; ng < 4; ++ng) {
                int n  = n0 + ng * 16 + l15;
                int ch = (kc * 4 + lh) ^ (n & 7);
                bf[ng] = *(const short8*)(Wb + n * 64 + ch * 8);
            }
            #pragma unroll
            for (int mg = 0; mg < 4; ++mg)
                #pragma unroll
                for (int ng = 0; ng < 4; ++ng)
                    acc[mg][ng] = __builtin_amdgcn_mfma_f32_16x16x32_bf16(
                        af[mg], bf[ng], acc[mg][ng], 0, 0, 0);
        }
    };

    float4 xA[8], xB[8];
    // prologue: queue after these issues = [xA:8, W0:4, xB:8]
    loadX(0, xA);
    stageW(0, 0);
    loadX(64, xB);
    writeX(0, xA);                                  // implicit wait: xA (vmcnt<=12)
    asm volatile("s_waitcnt vmcnt(8) lgkmcnt(0)" ::: "memory");  // W0 done; xB flies
    __builtin_amdgcn_sched_barrier(0);
    __builtin_amdgcn_s_barrier();
    __builtin_amdgcn_sched_barrier(0);

    // steady state: entering step t, queue = [x(t+1):8]; LDS has x(t),W(t).
    auto step = [&](int t, float4* XW, float4* XL) {
        const int buf = t & 1;
        if (t + 1 < 16) stageW((t + 1) * 64, buf ^ 1);   // +4  -> [x8, W4]
        if (t + 2 < 16) loadX((t + 2) * 64, XL);         // +8  -> [x8, W4, x8]
        compute(buf);
        if (t + 1 < 16) writeX(buf ^ 1, XW);             // implicit vmcnt(12): x(t+1)
        if (t < 15) {
            if (t < 14)
                asm volatile("s_waitcnt vmcnt(8) lgkmcnt(0)" ::: "memory");
            else
                asm volatile("s_waitcnt vmcnt(0) lgkmcnt(0)" ::: "memory");
            __builtin_amdgcn_sched_barrier(0);
            __builtin_amdgcn_s_barrier();
            __builtin_amdgcn_sched_barrier(0);
        }
    };

    for (int tt = 0; tt < 8; ++tt) {
        step(2 * tt,     xB, xA);    // writes x(t+1) from xB, loads x(t+2) into xA
        step(2 * tt + 1, xA, xB);
    }

    #pragma unroll
    for (int mg = 0; mg < 4; ++mg)
        #pragma unroll
        for (int ng = 0; ng < 4; ++ng)
            #pragma unroll
            for (int r = 0; r < 4; ++r) {
                int m = row0 + m0 + mg * 16 + lh * 4 + r;
                int n = n0 + ng * 16 + l15;
                outp[(size_t)m * Kn + n] = f2b(acc[mg][ng][r]);
            }
}

// ---------------------------------------------------------------------------
// attn: causal flash, split-s equal-work blocks (unchanged from R4).
// ---------------------------------------------------------------------------
__device__ const int g_job_qi[32] = {0, 1,1, 2,2,2, 3,3,3,3, 4,4,4,4,
                                     5,5,5,5,5, 6,6,6,6,6,6, 7,7,7,7,7,7,7};
__device__ const int g_sup_b[32] = {0, 0,4, 0,4,8, 0,4,8,12, 0,5,10,15,
                                    0,4,9,14,19, 0,4,9,14,18,23, 0,4,9,13,18,22,27};
__device__ const int g_sup_e[32] = {4, 4,8, 4,8,12, 4,8,12,16, 5,10,15,20,
                                    4,9,14,19,24, 4,9,14,18,23,28, 4,9,13,18,22,27,32};

__global__ __launch_bounds__(512, 2)
void attn_kernel(const u16* __restrict__ qg_, const u16* __restrict__ kg_,
                 const u16* __restrict__ vg_, u16* __restrict__ pO,
                 float* __restrict__ pM, float* __restrict__ pL)
{
    const int b   = blockIdx.x;
    const int job = blockIdx.y;
    const int qi  = g_job_qi[job];
    const int sb  = g_sup_b[job], se = g_sup_e[job];

    const u16* qw = qg_ + (size_t)b * Tn * Kn;
    const u16* kw = kg_ + (size_t)b * Tn * Kn;
    const u16* vw = vg_ + (size_t)b * Tn * Kn;

    const int tid  = threadIdx.x;
    const int lane = tid & 63;
    const int wid  = tid >> 6;
    const int l15  = lane & 15, lh = lane >> 4;

    const int q0 = qi * 256 + wid * 32;
    const int qmax_w = q0 + 31;

    __shared__ u16 lds[32768];

    short8 qf[2][4];
    #pragma unroll
    for (int g = 0; g < 2; ++g)
        #pragma unroll
        for (int kc = 0; kc < 4; ++kc)
            qf[g][kc] = *(const short8*)(qw + (size_t)(q0 + g * 16 + l15) * Kn
                                         + kc * 32 + lh * 8);

    f32x4 acc[8][2];
    #pragma unroll
    for (int dt = 0; dt < 8; ++dt)
        #pragma unroll
        for (int g = 0; g < 2; ++g) acc[dt][g] = (f32x4){0.f, 0.f, 0.f, 0.f};
    float m_g[2] = {NEGINF, NEGINF}, l_g[2] = {0.f, 0.f};

    const float scale = 0.08838834764831843f;

    auto stageK = [&](int sup, int buf) {
        const u16* src = kw + (size_t)sup * 64 * Kn;
        u16* dst = lds + buf * 8192;
        #pragma unroll
        for (int i = 0; i < 2; ++i) {
            int u = wid * 128 + i * 64 + lane;
            int row = u >> 4;
            int c16 = (u & 15) ^ (row & 7);
            load_lds16(src + (size_t)row * Kn + c16 * 8,
                       dst + (size_t)(wid * 128 + i * 64) * 8);
        }
    };
    auto loadV = [&](int sup, uint4* vr) {
        const u16* src = vw + (size_t)sup * 64 * Kn;
        #pragma unroll
        for (int r = 0; r < 2; ++r) {
            int s  = tid & 63;
            int u8 = (tid >> 6) + 8 * r;
            vr[r] = *(const uint4*)(src + (size_t)s * Kn + u8 * 8);
        }
    };
    auto writeV = [&](int buf, const uint4* vr) {
        u16* dst = lds + 16384 + buf * 8192;
        #pragma unroll
        for (int r = 0; r < 2; ++r) {
            int s  = tid & 63;
            int u8 = (tid >> 6) + 8 * r;
            const u16* e = (const u16*)&vr[r];
            #pragma unroll
            for (int j = 0; j < 8; ++j) {
                int d = u8 * 8 + j;
                dst[d * 64 + (((s >> 3) ^ j) << 3) + (s & 7)] = e[j];
            }
        }
    };

    uint4 vreg[2];
    stageK(sb, 0);
    loadV(sb, vreg);
    writeV(0, vreg);

    for (int sup = sb; sup < se; ++sup) {
        const int cur = (sup - sb) & 1;
        __syncthreads();
        const bool have_next = (sup + 1 < se);
        if (have_next) {
            stageK(sup + 1, cur ^ 1);
            loadV(sup + 1, vreg);
        }
        if (sup * 64 <= qmax_w) {
            const u16* Kb = lds + cur * 8192;
            const u16* Vb = lds + 16384 + cur * 8192;
            f32x4 sf[4][2];
            #pragma unroll
            for (int mt = 0; mt < 4; ++mt)
                #pragma unroll
                for (int g = 0; g < 2; ++g) sf[mt][g] = (f32x4){0.f,0.f,0.f,0.f};
            #pragma unroll
            for (int kc = 0; kc < 4; ++kc) {
                short8 a[4];
                #pragma unroll
                for (int mt = 0; mt < 4; ++mt) {
                    int row = mt * 16 + l15;
                    int ch  = (kc * 4 + lh) ^ (row & 7);
                    a[mt] = *(const short8*)(Kb + row * 128 + ch * 8);
                }
                #pragma unroll
                for (int mt = 0; mt < 4; ++mt)
                    #pragma unroll
                    for (int g = 0; g < 2; ++g)
                        sf[mt][g] = __builtin_amdgcn_mfma_f32_16x16x32_bf16(
                            a[mt], qf[g][kc], sf[mt][g], 0, 0, 0);
            }
            const int sbase = sup * 64;
            u32 upk[2][4][2];
            float alpha_g[2];
            #pragma unroll
            for (int g = 0; g < 2; ++g) {
                const int qg = q0 + g * 16 + l15;
                float pv[16];
                float pm = NEGINF;
                #pragma unroll
                for (int mt = 0; mt < 4; ++mt)
                    #pragma unroll
                    for (int r = 0; r < 4; ++r) {
                        int sg = sbase + mt * 16 + lh * 4 + r;
                        float vv = sf[mt][g][r] * scale;
                        vv = (sg > qg) ? NEGINF : vv;
                        pv[mt * 4 + r] = vv;
                        pm = fmaxf(pm, vv);
                    }
                pm = fmaxf(pm, __shfl_xor(pm, 16));
                pm = fmaxf(pm, __shfl_xor(pm, 32));
                float mn  = fmaxf(m_g[g], pm);
                float mns = (mn == NEGINF) ? 0.f : mn;
                float al  = __expf(m_g[g] - mns);
                m_g[g] = mn;
                alpha_g[g] = al;
                float ps = 0.f;
                #pragma unroll
                for (int i = 0; i < 16; ++i) { pv[i] = __expf(pv[i] - mns); ps += pv[i]; }
                ps += __shfl_xor(ps, 16);
                ps += __shfl_xor(ps, 32);
                l_g[g] = l_g[g] * al + ps;
                #pragma unroll
                for (int mt = 0; mt < 4; ++mt)
                    #pragma unroll
                    for (int h = 0; h < 2; ++h)
                        upk[g][mt][h] = (u32)f2b(pv[mt * 4 + 2 * h])
                                      | ((u32)f2b(pv[mt * 4 + 2 * h + 1]) << 16);
            }
            #pragma unroll
            for (int dt = 0; dt < 8; ++dt)
                #pragma unroll
                for (int g = 0; g < 2; ++g)
                    acc[dt][g] *= alpha_g[g];
            #pragma unroll
            for (int ks = 0; ks < 2; ++ks) {
                short8 pf[2];
                #pragma unroll
                for (int g = 0; g < 2; ++g) {
                    union { u32 w[4]; short8 v; } uu;
                    #pragma unroll
                    for (int hp = 0; hp < 4; ++hp) {
                        int srcLane = l15 + 16 * ((lh & 1) * 2 + (hp >> 1));
                        u32 vA = __shfl(upk[g][2 * ks][hp & 1], srcLane, 64);
                        u32 vB = __shfl(upk[g][2 * ks + 1][hp & 1], srcLane, 64);
                        uu.w[hp] = (lh < 2) ? vA : vB;
                    }
                    pf[g] = uu.v;
                }
                #pragma unroll
                for (int dt = 0; dt < 8; ++dt) {
                    int d  = dt * 16 + l15;
                    int ch = (ks * 4 + lh) ^ (d & 7);
                    short8 av = *(const short8*)(Vb + d * 64 + ch * 8);
                    #pragma unroll
                    for (int g = 0; g < 2; ++g)
                        acc[dt][g] = __builtin_amdgcn_mfma_f32_16x16x32_bf16(
                            av, pf[g], acc[dt][g], 0, 0, 0);
                }
            }
        }
        if (have_next) writeV(cur ^ 1, vreg);
    }

    const size_t slotrow = ((size_t)b * 32 + job) * 256 + wid * 32;
    #pragma unroll
    for (int g = 0; g < 2; ++g) {
        size_t row = slotrow + g * 16 + l15;
        #pragma unroll
        for (int dt = 0; dt < 8; ++dt) {
            ushort4 o = { f2b(acc[dt][g][0]), f2b(acc[dt][g][1]),
                          f2b(acc[dt][g][2]), f2b(acc[dt][g][3]) };
            *(ushort4*)(pO + row * 128 + dt * 16 + lh * 4) = o;
        }
        if (lh == 0) {
            pM[row] = m_g[g];
            pL[row] = l_g[g];
        }
    }
}

// ---------------------------------------------------------------------------
// merge v2 (unchanged from R4).
// ---------------------------------------------------------------------------
__device__ const int g_cnt[8] = {1, 2, 3, 4, 4, 5, 6, 7};
__device__ const int g_s0[8]  = {0, 1, 3, 6, 10, 14, 19, 25};

__global__ __launch_bounds__(256)
void merge_kernel(const u16* __restrict__ pO, const float* __restrict__ pM,
                  const float* __restrict__ pL, float* __restrict__ out)
{
    const int bid = blockIdx.x;
    const int b   = bid >> 8;
    const int rem = bid & 255;
    const int qi  = rem >> 5;
    const int rg  = rem & 31;
    const int c = g_cnt[qi], s0 = g_s0[qi];
    const int tid = threadIdx.x;
    const int r8 = tid >> 5;
    const int dg = tid & 31;

    const int row = rg * 8 + r8;
    const size_t base = ((size_t)b * 32 + s0) * 256 + row;

    float mv[8];
    float M = NEGINF;
    #pragma unroll
    for (int i = 0; i < 8; ++i)
        if (i < c) { mv[i] = pM[base + (size_t)i * 256]; M = fmaxf(M, mv[i]); }
    float L = 0.f, w[8];
    #pragma unroll
    for (int i = 0; i < 8; ++i)
        if (i < c) {
            float e = __expf(mv[i] - M);
            L += pL[base + (size_t)i * 256] * e;
            w[i] = e;
        }
    const float invL = 1.f / L;

    float4 o = {0.f, 0.f, 0.f, 0.f};
    #pragma unroll
    for (int i = 0; i < 8; ++i)
        if (i < c) {
            ushort4 p = *(const ushort4*)(pO + (base + (size_t)i * 256) * 128 + dg * 4);
            float wi = w[i] * invL;
            o.x = fmaf(wi, b2f(p.x), o.x);
            o.y = fmaf(wi, b2f(p.y), o.y);
            o.z = fmaf(wi, b2f(p.z), o.z);
            o.w = fmaf(wi, b2f(p.w), o.w);
        }
    *(float4*)(out + ((size_t)b * Tn + qi * 256 + row) * Kn + dg * 4) = o;
}

// ---------------------------------------------------------------------------
extern "C" void kernel_launch(void* const* d_in, const int* in_sizes, int n_in,
                              void* d_out, int out_size, void* d_ws, size_t ws_size,
                              hipStream_t stream)
{
    const float* x  = (const float*)d_in[0];
    const float* Wq = (const float*)d_in[1];
    const float* Wk = (const float*)d_in[2];
    const float* Wv = (const float*)d_in[3];
    float* out = (float*)d_out;

    u16* ws = (u16*)d_ws;
    const size_t btk = (size_t)Bn * Tn * Kn;       // 2,097,152
    u16* q  = ws;
    u16* k  = ws + btk;
    u16* v  = ws + 2 * btk;
    u16* Wt = ws + 3 * btk;                        // 393216 u16
    u16* pO = ws + 3 * btk + 393216;               // 8,388,608 u16
    float* pM = (float*)(pO + (size_t)8388608);    // 65536 f32
    float* pL = pM + 65536;                        // 65536 f32
    // total ws usage ~30.7 MB

    prep_kernel<<<384, 256, 0, stream>>>(Wq, Wk, Wv, Wt);
    proj4_kernel<<<384, 256, 0, stream>>>(x, Wt, ws);
    attn_kernel<<<dim3(Bn, 32), 512, 0, stream>>>(q, k, v, pO, pM, pL);
    merge_kernel<<<2048, 256, 0, stream>>>(pO, pM, pL, out);
}

// Round 8
// 67.077 us; speedup vs baseline: 1.1347x; 1.0545x over previous
//
#include <hip/hip_runtime.h>
#include <cmath>

#define Bn 8
#define Tn 2048
#define Cn 1024
#define Kn 128

typedef __attribute__((ext_vector_type(8))) short short8;
typedef __attribute__((ext_vector_type(4))) float f32x4;
typedef unsigned short u16;
typedef unsigned int u32;

#define NEGINF (-__builtin_huge_valf())

__device__ __forceinline__ u16 f2b(float f) {
    u32 u = __float_as_uint(f);
    u32 r = (u + 0x7FFFu + ((u >> 16) & 1u)) >> 16;
    return (u16)r;
}
__device__ __forceinline__ float b2f(u16 v) {
    u32 u = ((u32)v) << 16;
    return __uint_as_float(u);
}
// packed fp32x2 -> bf16x2 (lo -> [15:0], hi -> [31:16]), RNE.
__device__ __forceinline__ u32 cvtpk(float lo, float hi) {
    u32 r;
    asm("v_cvt_pk_bf16_f32 %0, %1, %2" : "=v"(r) : "v"(lo), "v"(hi));
    return r;
}

__device__ __forceinline__ void load_lds16(const u16* g, u16* l) {
    __builtin_amdgcn_global_load_lds(
        (const __attribute__((address_space(1))) u32*)(g),
        (__attribute__((address_space(3))) u32*)(l), 16, 0, 0);
}

// ---------------------------------------------------------------------------
// prep: W [1024 c][128 n] fp32 -> W^T bf16 [3][128 n][1024 c]
// ---------------------------------------------------------------------------
__global__ __launch_bounds__(256)
void prep_kernel(const float* __restrict__ Wq, const float* __restrict__ Wk,
                 const float* __restrict__ Wv, u16* __restrict__ Wt)
{
    int id = blockIdx.x * 256 + threadIdx.x;
    int w   = id >> 15;
    int rem = id & 32767;
    int c   = rem >> 5;
    int n4  = (rem & 31) << 2;
    const float* W = (w == 0) ? Wq : (w == 1) ? Wk : Wv;
    float4 v = *(const float4*)(W + (size_t)c * Kn + n4);
    u16* dst = Wt + (size_t)w * Kn * Cn;
    dst[(size_t)(n4 + 0) * Cn + c] = f2b(v.x);
    dst[(size_t)(n4 + 1) * Cn + c] = f2b(v.y);
    dst[(size_t)(n4 + 2) * Cn + c] = f2b(v.z);
    dst[(size_t)(n4 + 3) * Cn + c] = f2b(v.w);
}

// ---------------------------------------------------------------------------
// proj5: qkv[w] = x @ W[w]. 64x128 tile -> 768 blocks (3/CU), 4 waves x
// (32x64, acc 2x4), BK=64. LDS 48KB: x(bf16) 2x8KB + W 2x16KB, double-
// buffered, counted-vmcnt raw-barrier pipeline (x 2-deep reg prefetch).
// ---------------------------------------------------------------------------
__global__ __launch_bounds__(256)
void proj5_kernel(const float* __restrict__ x, const u16* __restrict__ Wt,
                  u16* __restrict__ qkv)
{
    const int bid = blockIdx.x;
    const int g8  = bid >> 3, xr = bid & 7;      // 96 groups of 8 (same XCD)
    const int w   = g8 % 3;
    const int rt  = (g8 / 3) * 8 + xr;           // 0..255
    const u16* wtg = Wt + (size_t)w * Kn * Cn;   // [128 n][1024 c]
    u16* outp = qkv + (size_t)w * Bn * Tn * Kn;
    const int row0 = rt * 64;
    const int tid  = threadIdx.x;
    const int lane = tid & 63;
    const int wid  = tid >> 6;
    const int l15  = lane & 15, lh = lane >> 4;
    const int m0 = (wid >> 1) * 32, n0 = (wid & 1) * 64;

    // u16 units: xs0 @0 [64][64], xs1 @4096, wt0 @8192 [128][64], wt1 @16384.
    __shared__ u16 lds[24576];

    auto stageW = [&](int kk, int buf) {
        #pragma unroll
        for (int i = 0; i < 4; ++i) {
            int u = tid + i * 256;               // 0..1023 16B-chunks
            int n = u >> 3, c8 = u & 7;
            load_lds16(wtg + (size_t)n * Cn + kk + ((c8 ^ (n & 7)) << 3),
                       lds + 8192 + buf * 8192 + u * 8);
        }
    };
    auto loadX = [&](int kk, float4* xr4) {
        #pragma unroll
        for (int i = 0; i < 2; ++i) {
            int u = tid + i * 256;               // 0..511 8-float chunks
            int r = u >> 3, c8 = u & 7;
            const float* s = x + (size_t)(row0 + r) * Cn + kk + c8 * 8;
            xr4[2 * i]     = *(const float4*)(s);
            xr4[2 * i + 1] = *(const float4*)(s + 4);
        }
    };
    auto writeX = [&](int buf, const float4* xr4) {
        u16* dst = lds + buf * 4096;
        #pragma unroll
        for (int i = 0; i < 2; ++i) {
            int u = tid + i * 256;
            int r = u >> 3, c8 = u & 7;
            uint4 pk;
            pk.x = cvtpk(xr4[2 * i].x,     xr4[2 * i].y);
            pk.y = cvtpk(xr4[2 * i].z,     xr4[2 * i].w);
            pk.z = cvtpk(xr4[2 * i + 1].x, xr4[2 * i + 1].y);
            pk.w = cvtpk(xr4[2 * i + 1].z, xr4[2 * i + 1].w);
            *(uint4*)(dst + r * 64 + ((c8 ^ (r & 7)) << 3)) = pk;
        }
    };

    f32x4 acc[2][4];
    #pragma unroll
    for (int i = 0; i < 2; ++i)
        #pragma unroll
        for (int j = 0; j < 4; ++j) acc[i][j] = (f32x4){0.f, 0.f, 0.f, 0.f};

    auto compute = [&](int buf) {
        const u16* Xb = lds + buf * 4096;
        const u16* Wb = lds + 8192 + buf * 8192;
        #pragma unroll
        for (int kc = 0; kc < 2; ++kc) {
            short8 af[2], bf[4];
            #pragma unroll
            for (int mg = 0; mg < 2; ++mg) {
                int row = m0 + mg * 16 + l15;
                int ch  = (kc * 4 + lh) ^ (row & 7);
                af[mg] = *(const short8*)(Xb + row * 64 + ch * 8);
            }
            #pragma unroll
            for (int ng = 0; ng < 4; ++ng) {
                int n  = n0 + ng * 16 + l15;
                int ch = (kc * 4 + lh) ^ (n & 7);
                bf[ng] = *(const short8*)(Wb + n * 64 + ch * 8);
            }
            #pragma unroll
            for (int mg = 0; mg < 2; ++mg)
                #pragma unroll
                for (int ng = 0; ng < 4; ++ng)
                    acc[mg][ng] = __builtin_amdgcn_mfma_f32_16x16x32_bf16(
                        af[mg], bf[ng], acc[mg][ng], 0, 0, 0);
        }
    };

    float4 xA[4], xB[4];
    // prologue: queue after issues = [xA:4, W0:4, xB:4]
    loadX(0, xA);
    stageW(0, 0);
    loadX(64, xB);
    writeX(0, xA);                                // implicit wait drains xA
    asm volatile("s_waitcnt vmcnt(4) lgkmcnt(0)" ::: "memory");  // W0 done; xB flies
    __builtin_amdgcn_sched_barrier(0);
    __builtin_amdgcn_s_barrier();
    __builtin_amdgcn_sched_barrier(0);

    // steady state: entering step t, queue = [x(t+1):4]; LDS has x(t),W(t).
    auto step = [&](int t, float4* XW, float4* XL) {
        const int buf = t & 1;
        if (t + 1 < 16) stageW((t + 1) * 64, buf ^ 1);   // +4 -> [x4, W4]
        if (t + 2 < 16) loadX((t + 2) * 64, XL);         // +4 -> [x4, W4, x4]
        compute(buf);
        if (t + 1 < 16) writeX(buf ^ 1, XW);             // implicit wait: x(t+1)
        if (t < 15) {
            if (t < 14)
                asm volatile("s_waitcnt vmcnt(4) lgkmcnt(0)" ::: "memory");
            else
                asm volatile("s_waitcnt vmcnt(0) lgkmcnt(0)" ::: "memory");
            __builtin_amdgcn_sched_barrier(0);
            __builtin_amdgcn_s_barrier();
            __builtin_amdgcn_sched_barrier(0);
        }
    };

    for (int tt = 0; tt < 8; ++tt) {
        step(2 * tt,     xB, xA);
        step(2 * tt + 1, xA, xB);
    }

    #pragma unroll
    for (int mg = 0; mg < 2; ++mg)
        #pragma unroll
        for (int ng = 0; ng < 4; ++ng)
            #pragma unroll
            for (int r = 0; r < 4; ++r) {
                int m = row0 + m0 + mg * 16 + lh * 4 + r;
                int n = n0 + ng * 16 + l15;
                outp[(size_t)m * Kn + n] = f2b(acc[mg][ng][r]);
            }
}

// ---------------------------------------------------------------------------
// attn: causal flash, split-s equal-work blocks (unchanged from R4).
// ---------------------------------------------------------------------------
__device__ const int g_job_qi[32] = {0, 1,1, 2,2,2, 3,3,3,3, 4,4,4,4,
                                     5,5,5,5,5, 6,6,6,6,6,6, 7,7,7,7,7,7,7};
__device__ const int g_sup_b[32] = {0, 0,4, 0,4,8, 0,4,8,12, 0,5,10,15,
                                    0,4,9,14,19, 0,4,9,14,18,23, 0,4,9,13,18,22,27};
__device__ const int g_sup_e[32] = {4, 4,8, 4,8,12, 4,8,12,16, 5,10,15,20,
                                    4,9,14,19,24, 4,9,14,18,23,28, 4,9,13,18,22,27,32};

__global__ __launch_bounds__(512, 2)
void attn_kernel(const u16* __restrict__ qg_, const u16* __restrict__ kg_,
                 const u16* __restrict__ vg_, u16* __restrict__ pO,
                 float* __restrict__ pM, float* __restrict__ pL)
{
    const int b   = blockIdx.x;
    const int job = blockIdx.y;
    const int qi  = g_job_qi[job];
    const int sb  = g_sup_b[job], se = g_sup_e[job];

    const u16* qw = qg_ + (size_t)b * Tn * Kn;
    const u16* kw = kg_ + (size_t)b * Tn * Kn;
    const u16* vw = vg_ + (size_t)b * Tn * Kn;

    const int tid  = threadIdx.x;
    const int lane = tid & 63;
    const int wid  = tid >> 6;
    const int l15  = lane & 15, lh = lane >> 4;

    const int q0 = qi * 256 + wid * 32;
    const int qmax_w = q0 + 31;

    __shared__ u16 lds[32768];

    short8 qf[2][4];
    #pragma unroll
    for (int g = 0; g < 2; ++g)
        #pragma unroll
        for (int kc = 0; kc < 4; ++kc)
            qf[g][kc] = *(const short8*)(qw + (size_t)(q0 + g * 16 + l15) * Kn
                                         + kc * 32 + lh * 8);

    f32x4 acc[8][2];
    #pragma unroll
    for (int dt = 0; dt < 8; ++dt)
        #pragma unroll
        for (int g = 0; g < 2; ++g) acc[dt][g] = (f32x4){0.f, 0.f, 0.f, 0.f};
    float m_g[2] = {NEGINF, NEGINF}, l_g[2] = {0.f, 0.f};

    const float scale = 0.08838834764831843f;

    auto stageK = [&](int sup, int buf) {
        const u16* src = kw + (size_t)sup * 64 * Kn;
        u16* dst = lds + buf * 8192;
        #pragma unroll
        for (int i = 0; i < 2; ++i) {
            int u = wid * 128 + i * 64 + lane;
            int row = u >> 4;
            int c16 = (u & 15) ^ (row & 7);
            load_lds16(src + (size_t)row * Kn + c16 * 8,
                       dst + (size_t)(wid * 128 + i * 64) * 8);
        }
    };
    auto loadV = [&](int sup, uint4* vr) {
        const u16* src = vw + (size_t)sup * 64 * Kn;
        #pragma unroll
        for (int r = 0; r < 2; ++r) {
            int s  = tid & 63;
            int u8 = (tid >> 6) + 8 * r;
            vr[r] = *(const uint4*)(src + (size_t)s * Kn + u8 * 8);
        }
    };
    auto writeV = [&](int buf, const uint4* vr) {
        u16* dst = lds + 16384 + buf * 8192;
        #pragma unroll
        for (int r = 0; r < 2; ++r) {
            int s  = tid & 63;
            int u8 = (tid >> 6) + 8 * r;
            const u16* e = (const u16*)&vr[r];
            #pragma unroll
            for (int j = 0; j < 8; ++j) {
                int d = u8 * 8 + j;
                dst[d * 64 + (((s >> 3) ^ j) << 3) + (s & 7)] = e[j];
            }
        }
    };

    uint4 vreg[2];
    stageK(sb, 0);
    loadV(sb, vreg);
    writeV(0, vreg);

    for (int sup = sb; sup < se; ++sup) {
        const int cur = (sup - sb) & 1;
        __syncthreads();
        const bool have_next = (sup + 1 < se);
        if (have_next) {
            stageK(sup + 1, cur ^ 1);
            loadV(sup + 1, vreg);
        }
        if (sup * 64 <= qmax_w) {
            const u16* Kb = lds + cur * 8192;
            const u16* Vb = lds + 16384 + cur * 8192;
            f32x4 sf[4][2];
            #pragma unroll
            for (int mt = 0; mt < 4; ++mt)
                #pragma unroll
                for (int g = 0; g < 2; ++g) sf[mt][g] = (f32x4){0.f,0.f,0.f,0.f};
            #pragma unroll
            for (int kc = 0; kc < 4; ++kc) {
                short8 a[4];
                #pragma unroll
                for (int mt = 0; mt < 4; ++mt) {
                    int row = mt * 16 + l15;
                    int ch  = (kc * 4 + lh) ^ (row & 7);
                    a[mt] = *(const short8*)(Kb + row * 128 + ch * 8);
                }
                #pragma unroll
                for (int mt = 0; mt < 4; ++mt)
                    #pragma unroll
                    for (int g = 0; g < 2; ++g)
                        sf[mt][g] = __builtin_amdgcn_mfma_f32_16x16x32_bf16(
                            a[mt], qf[g][kc], sf[mt][g], 0, 0, 0);
            }
            const int sbase = sup * 64;
            u32 upk[2][4][2];
            float alpha_g[2];
            #pragma unroll
            for (int g = 0; g < 2; ++g) {
                const int qg = q0 + g * 16 + l15;
                float pv[16];
                float pm = NEGINF;
                #pragma unroll
                for (int mt = 0; mt < 4; ++mt)
                    #pragma unroll
                    for (int r = 0; r < 4; ++r) {
                        int sg = sbase + mt * 16 + lh * 4 + r;
                        float vv = sf[mt][g][r] * scale;
                        vv = (sg > qg) ? NEGINF : vv;
                        pv[mt * 4 + r] = vv;
                        pm = fmaxf(pm, vv);
                    }
                pm = fmaxf(pm, __shfl_xor(pm, 16));
                pm = fmaxf(pm, __shfl_xor(pm, 32));
                float mn  = fmaxf(m_g[g], pm);
                float mns = (mn == NEGINF) ? 0.f : mn;
                float al  = __expf(m_g[g] - mns);
                m_g[g] = mn;
                alpha_g[g] = al;
                float ps = 0.f;
                #pragma unroll
                for (int i = 0; i < 16; ++i) { pv[i] = __expf(pv[i] - mns); ps += pv[i]; }
                ps += __shfl_xor(ps, 16);
                ps += __shfl_xor(ps, 32);
                l_g[g] = l_g[g] * al + ps;
                #pragma unroll
                for (int mt = 0; mt < 4; ++mt)
                    #pragma unroll
                    for (int h = 0; h < 2; ++h)
                        upk[g][mt][h] = (u32)f2b(pv[mt * 4 + 2 * h])
                                      | ((u32)f2b(pv[mt * 4 + 2 * h + 1]) << 16);
            }
            #pragma unroll
            for (int dt = 0; dt < 8; ++dt)
                #pragma unroll
                for (int g = 0; g < 2; ++g)
                    acc[dt][g] *= alpha_g[g];
            #pragma unroll
            for (int ks = 0; ks < 2; ++ks) {
                short8 pf[2];
                #pragma unroll
                for (int g = 0; g < 2; ++g) {
                    union { u32 w[4]; short8 v; } uu;
                    #pragma unroll
                    for (int hp = 0; hp < 4; ++hp) {
                        int srcLane = l15 + 16 * ((lh & 1) * 2 + (hp >> 1));
                        u32 vA = __shfl(upk[g][2 * ks][hp & 1], srcLane, 64);
                        u32 vB = __shfl(upk[g][2 * ks + 1][hp & 1], srcLane, 64);
                        uu.w[hp] = (lh < 2) ? vA : vB;
                    }
                    pf[g] = uu.v;
                }
                #pragma unroll
                for (int dt = 0; dt < 8; ++dt) {
                    int d  = dt * 16 + l15;
                    int ch = (ks * 4 + lh) ^ (d & 7);
                    short8 av = *(const short8*)(Vb + d * 64 + ch * 8);
                    #pragma unroll
                    for (int g = 0; g < 2; ++g)
                        acc[dt][g] = __builtin_amdgcn_mfma_f32_16x16x32_bf16(
                            av, pf[g], acc[dt][g], 0, 0, 0);
                }
            }
        }
        if (have_next) writeV(cur ^ 1, vreg);
    }

    const size_t slotrow = ((size_t)b * 32 + job) * 256 + wid * 32;
    #pragma unroll
    for (int g = 0; g < 2; ++g) {
        size_t row = slotrow + g * 16 + l15;
        #pragma unroll
        for (int dt = 0; dt < 8; ++dt) {
            ushort4 o = { f2b(acc[dt][g][0]), f2b(acc[dt][g][1]),
                          f2b(acc[dt][g][2]), f2b(acc[dt][g][3]) };
            *(ushort4*)(pO + row * 128 + dt * 16 + lh * 4) = o;
        }
        if (lh == 0) {
            pM[row] = m_g[g];
            pL[row] = l_g[g];
        }
    }
}

// ---------------------------------------------------------------------------
// merge v2 (unchanged from R4).
// ---------------------------------------------------------------------------
__device__ const int g_cnt[8] = {1, 2, 3, 4, 4, 5, 6, 7};
__device__ const int g_s0[8]  = {0, 1, 3, 6, 10, 14, 19, 25};

__global__ __launch_bounds__(256)
void merge_kernel(const u16* __restrict__ pO, const float* __restrict__ pM,
                  const float* __restrict__ pL, float* __restrict__ out)
{
    const int bid = blockIdx.x;
    const int b   = bid >> 8;
    const int rem = bid & 255;
    const int qi  = rem >> 5;
    const int rg  = rem & 31;
    const int c = g_cnt[qi], s0 = g_s0[qi];
    const int tid = threadIdx.x;
    const int r8 = tid >> 5;
    const int dg = tid & 31;

    const int row = rg * 8 + r8;
    const size_t base = ((size_t)b * 32 + s0) * 256 + row;

    float mv[8];
    float M = NEGINF;
    #pragma unroll
    for (int i = 0; i < 8; ++i)
        if (i < c) { mv[i] = pM[base + (size_t)i * 256]; M = fmaxf(M, mv[i]); }
    float L = 0.f, w[8];
    #pragma unroll
    for (int i = 0; i < 8; ++i)
        if (i < c) {
            float e = __expf(mv[i] - M);
            L += pL[base + (size_t)i * 256] * e;
            w[i] = e;
        }
    const float invL = 1.f / L;

    float4 o = {0.f, 0.f, 0.f, 0.f};
    #pragma unroll
    for (int i = 0; i < 8; ++i)
        if (i < c) {
            ushort4 p = *(const ushort4*)(pO + (base + (size_t)i * 256) * 128 + dg * 4);
            float wi = w[i] * invL;
            o.x = fmaf(wi, b2f(p.x), o.x);
            o.y = fmaf(wi, b2f(p.y), o.y);
            o.z = fmaf(wi, b2f(p.z), o.z);
            o.w = fmaf(wi, b2f(p.w), o.w);
        }
    *(float4*)(out + ((size_t)b * Tn + qi * 256 + row) * Kn + dg * 4) = o;
}

// ---------------------------------------------------------------------------
extern "C" void kernel_launch(void* const* d_in, const int* in_sizes, int n_in,
                              void* d_out, int out_size, void* d_ws, size_t ws_size,
                              hipStream_t stream)
{
    const float* x  = (const float*)d_in[0];
    const float* Wq = (const float*)d_in[1];
    const float* Wk = (const float*)d_in[2];
    const float* Wv = (const float*)d_in[3];
    float* out = (float*)d_out;

    u16* ws = (u16*)d_ws;
    const size_t btk = (size_t)Bn * Tn * Kn;       // 2,097,152
    u16* q  = ws;
    u16* k  = ws + btk;
    u16* v  = ws + 2 * btk;
    u16* Wt = ws + 3 * btk;                        // 393216 u16
    u16* pO = ws + 3 * btk + 393216;               // 8,388,608 u16
    float* pM = (float*)(pO + (size_t)8388608);    // 65536 f32
    float* pL = pM + 65536;                        // 65536 f32
    // total ws usage ~30.7 MB

    prep_kernel<<<384, 256, 0, stream>>>(Wq, Wk, Wv, Wt);
    proj5_kernel<<<768, 256, 0, stream>>>(x, Wt, ws);
    attn_kernel<<<dim3(Bn, 32), 512, 0, stream>>>(q, k, v, pO, pM, pL);
    merge_kernel<<<2048, 256, 0, stream>>>(pO, pM, pL, out);
}